// Round 8
// baseline (1013.244 us; speedup 1.0000x reference)
//
#include <hip/hip_runtime.h>
#include <stdint.h>

#define B_DIM 512
#define I_DIM 128
#define H_DIM 128
#define G_DIM 384
#define STEPS 511   // reference scans t = 0..T-2

typedef __attribute__((ext_vector_type(8))) short bf16x8;
typedef __attribute__((ext_vector_type(4))) float f32x4;
typedef _Float16 half8_t __attribute__((ext_vector_type(8)));

__device__ __forceinline__ unsigned bf16rne(float f) {
  unsigned u = __float_as_uint(f);
  return (u + 0x7fffu + ((u >> 16) & 1u)) >> 16;
}
__device__ __forceinline__ short bf16s(float f) { return (short)bf16rne(f); }

// Barrier draining ONLY LDS ops; global prefetches stay in flight across it.
#define BAR_LDS() asm volatile("s_waitcnt lgkmcnt(0)\n\ts_barrier" ::: "memory")

// ---------------------------------------------------------------------------
// Kernel A (MFMA): xp[row][g] = x[row][:].Wih[g][:] + bih[g] (+bhh[g] folded
// for the r,z gate thirds). fp16 output. Unchanged from round 6 (verified).
// ---------------------------------------------------------------------------
__global__ __launch_bounds__(512, 2) void k_xproj(
    const float* __restrict__ xch, const float* __restrict__ Wih,
    const float* __restrict__ bih, const float* __restrict__ bhh,
    _Float16* __restrict__ xp) {
  __shared__ __align__(16) char As[128 * 256];  // 32 KB bf16 A tile
  const int tid = threadIdx.x;
  const int lane = tid & 63;
  const int wave = tid >> 6;
  const int mh = wave & 1, nh = wave >> 1;
  const int l15 = lane & 15, l4 = lane >> 4;

  const float4* xs = (const float4*)(xch + (size_t)blockIdx.x * 128 * I_DIM);
#pragma unroll
  for (int q = 0; q < 8; ++q) {
    const int fi = tid + 512 * q;
    const int row = fi >> 5, kq = fi & 31;
    const float4 v = xs[fi];
    uint2 p;
    p.x = bf16rne(v.x) | (bf16rne(v.y) << 16);
    p.y = bf16rne(v.z) | (bf16rne(v.w) << 16);
    *(uint2*)(As + (row << 8) + ((kq << 3) ^ ((row & 7) << 4))) = p;
  }

  bf16x8 bf[6][4];
  float bv[6];
#pragma unroll
  for (int nf = 0; nf < 6; ++nf) {
    const int col = nh * 96 + nf * 16 + l15;
    bv[nf] = bih[col] + (col < 256 ? bhh[col] : 0.f);
#pragma unroll
    for (int ks = 0; ks < 4; ++ks) {
      const float* wr = Wih + (size_t)col * I_DIM + ks * 32 + l4 * 8;
      const float4 wa = *(const float4*)wr;
      const float4 wb = *(const float4*)(wr + 4);
      bf16x8 b;
      b[0] = bf16s(wa.x); b[1] = bf16s(wa.y); b[2] = bf16s(wa.z); b[3] = bf16s(wa.w);
      b[4] = bf16s(wb.x); b[5] = bf16s(wb.y); b[6] = bf16s(wb.z); b[7] = bf16s(wb.w);
      bf[nf][ks] = b;
    }
  }
  __syncthreads();

  f32x4 acc[4][6];
#pragma unroll
  for (int m = 0; m < 4; ++m)
#pragma unroll
    for (int nf = 0; nf < 6; ++nf) acc[m][nf] = (f32x4){0.f, 0.f, 0.f, 0.f};

#pragma unroll
  for (int ks = 0; ks < 4; ++ks) {
#pragma unroll
    for (int m = 0; m < 4; ++m) {
      const int arow = mh * 64 + m * 16 + l15;
      const int kbyte = ks * 64 + l4 * 16;
      const bf16x8 a =
          *(const bf16x8*)(As + (arow << 8) + (kbyte ^ ((arow & 7) << 4)));
#pragma unroll
      for (int nf = 0; nf < 6; ++nf)
        acc[m][nf] =
            __builtin_amdgcn_mfma_f32_16x16x32_bf16(a, bf[nf][ks], acc[m][nf], 0, 0, 0);
    }
  }

#pragma unroll
  for (int m = 0; m < 4; ++m) {
    const size_t row0 = (size_t)blockIdx.x * 128 + mh * 64 + m * 16 + l4 * 4;
#pragma unroll
    for (int nf = 0; nf < 6; ++nf) {
      const int col = nh * 96 + nf * 16 + l15;
#pragma unroll
      for (int r = 0; r < 4; ++r)
        xp[(row0 + r) * G_DIM + col] = (_Float16)(acc[m][nf][r] + bv[nf]);
    }
  }
}

// ---------------------------------------------------------------------------
// Kernel B: MFMA GRU recurrence, 16 rows/block. 32 blocks x 512 threads
// (8 waves, 2/SIMD). Wave w owns gate-tiles {w, w+8, w+16} (cols 16w..16w+15
// of r, z, n): B-frags (W_hh, f16) register-resident 48 VGPR, loaded once.
// Per step: 4 ds_read_b128 A-frags from swizzled h-tile -> 12 MFMA ->
// lane-local gate math for (b=4*(lane>>4)+r, u=16w+(lane&15)) -> f16 hnew
// write to other h-buffer -> ONE lgkm-only barrier. Decode: shfl-xor over
// 16-lane group -> pd ring; NLL 1 step behind on wave-0 lanes 0-15.
// ---------------------------------------------------------------------------
__global__ __launch_bounds__(512, 2) void k_rec(
    const _Float16* __restrict__ xp, const float* __restrict__ gt,
    const float* __restrict__ Whh, const float* __restrict__ bhh,
    const float* __restrict__ Wdec, const float* __restrict__ bdec,
    float* __restrict__ ws_h, float* __restrict__ nll_part,
    int t0, int t1, int first) {
  __shared__ __align__(16) _Float16 hT[2][16 * 128];  // swizzled h, dbuf, 8 KB
  __shared__ __align__(16) float pd[2][8][16];        // decode partial ring

  const int tid = threadIdx.x;
  const int lane = tid & 63;
  const int w = tid >> 6;            // wave id = tile t
  const int l15 = lane & 15, l4 = lane >> 4;
  const int row0 = blockIdx.x * 16;
  const int u = w * 16 + l15;        // unit this lane owns for gate math
  const int nT = t1 - t0;

  // ---- one-time: B fragments (W_hh rows for cols {u,128+u,256+u}) ----
  half8_t bfr[3][4];
#pragma unroll
  for (int g3 = 0; g3 < 3; ++g3) {
    const int col = g3 * H_DIM + u;
#pragma unroll
    for (int ks = 0; ks < 4; ++ks) {
      const float* wr = Whh + (size_t)col * H_DIM + ks * 32 + l4 * 8;
      const float4 wa = *(const float4*)wr;
      const float4 wb = *(const float4*)(wr + 4);
      half8_t b;
      b[0] = (_Float16)wa.x; b[1] = (_Float16)wa.y;
      b[2] = (_Float16)wa.z; b[3] = (_Float16)wa.w;
      b[4] = (_Float16)wb.x; b[5] = (_Float16)wb.y;
      b[6] = (_Float16)wb.z; b[7] = (_Float16)wb.w;
      bfr[g3][ks] = b;
    }
  }
  const float bhn_u = bhh[2 * H_DIM + u];
  const float wdj = Wdec[u];
  const float bd0 = bdec[0];
  const int base_off = (row0 + l4 * 4) * G_DIM + u;  // xp lane base (elems)

  // ---- init h_old (fp32 regs) + h-tile buffer 0 (f16, swizzled) ----
  float h_old[4];
#pragma unroll
  for (int r = 0; r < 4; ++r) {
    const int b = l4 * 4 + r;
    h_old[r] = first ? 0.f : ws_h[(size_t)(row0 + b) * H_DIM + u];
    *(_Float16*)((char*)hT[0] + b * 256 + ((2 * u) ^ ((b & 7) << 4))) =
        (_Float16)h_old[r];
  }

  // ---- prologue: xp for step t0; gt for step t0+1 ----
  _Float16 xc[4][3];
  {
    const _Float16* xps = xp;  // lt = 0
#pragma unroll
    for (int r = 0; r < 4; ++r)
#pragma unroll
      for (int g3 = 0; g3 < 3; ++g3)
        xc[r][g3] = xps[base_off + r * G_DIM + g3 * H_DIM];
  }
  float g_hold = 0.f, nll0 = 0.f;
  if (tid < 16) g_hold = gt[(size_t)(t0 + 1) * B_DIM + row0 + tid];
  __syncthreads();

#pragma unroll 1
  for (int s = t0; s < t1; ++s) {
    const int lt = s - t0;
    // -- prefetch next step's xp + gt (consumed next step; fly over barrier)
    const int nlt = (lt + 1 < nT) ? lt + 1 : lt;
    const _Float16* xps = xp + (size_t)nlt * (B_DIM * G_DIM);
    _Float16 xn_[4][3];
#pragma unroll
    for (int r = 0; r < 4; ++r)
#pragma unroll
      for (int g3 = 0; g3 < 3; ++g3)
        xn_[r][g3] = xps[base_off + r * G_DIM + g3 * H_DIM];
    float g_fut = 0.f;
    if (tid < 16) g_fut = gt[(size_t)(s + 2 <= t1 ? s + 2 : t1) * B_DIM + row0 + tid];

    // -- A fragments: h[b=l15][k=ks*32+l4*8..] from swizzled tile
    const char* hb = (const char*)hT[lt & 1];
    half8_t af[4];
#pragma unroll
    for (int ks = 0; ks < 4; ++ks)
      af[ks] = *(const half8_t*)(hb + l15 * 256 +
                                 ((ks * 64 + l4 * 16) ^ ((l15 & 7) << 4)));

    // -- NLL for step s-1 on wave-0 lanes (stale pd; overlaps ds latency)
    if (tid < 16 && s > t0) {
      float p = bd0;
#pragma unroll
      for (int ww = 0; ww < 8; ++ww) p += pd[(lt - 1) & 1][ww][tid];
      const float C = 1.f / (1.f + __expf(-p));
      nll0 -= g_hold * __logf(C + 1e-4f) +
              (1.f - g_hold) * __logf(1.f - C + 1e-4f);
    }

    // -- 12 MFMA: preact[b][col] for this wave's r/z/n tiles
    f32x4 aR = (f32x4){0.f, 0.f, 0.f, 0.f};
    f32x4 aZ = (f32x4){0.f, 0.f, 0.f, 0.f};
    f32x4 aN = (f32x4){0.f, 0.f, 0.f, 0.f};
#pragma unroll
    for (int ks = 0; ks < 4; ++ks) {
      aR = __builtin_amdgcn_mfma_f32_16x16x32_f16(af[ks], bfr[0][ks], aR, 0, 0, 0);
      aZ = __builtin_amdgcn_mfma_f32_16x16x32_f16(af[ks], bfr[1][ks], aZ, 0, 0, 0);
      aN = __builtin_amdgcn_mfma_f32_16x16x32_f16(af[ks], bfr[2][ks], aN, 0, 0, 0);
    }

    // -- gate math, fully lane-local; write hnew to other h-buffer
    char* hw = (char*)hT[(lt + 1) & 1];
    float pvr[4];
#pragma unroll
    for (int r = 0; r < 4; ++r) {
      const float rp = aR[r] + (float)xc[r][0];   // bih+bhh_r folded in xp
      const float zp = aZ[r] + (float)xc[r][1];
      const float hn = aN[r] + bhn_u;
      const float r_ = 1.f / (1.f + __expf(-rp));
      const float z_ = 1.f / (1.f + __expf(-zp));
      const float e2 = __expf(2.f * ((float)xc[r][2] + r_ * hn));
      const float n_ = 1.f - 2.f / (e2 + 1.f);
      const float hnew = (1.f - z_) * n_ + z_ * h_old[r];
      h_old[r] = hnew;
      const int b = l4 * 4 + r;
      *(_Float16*)(hw + b * 256 + ((2 * u) ^ ((b & 7) << 4))) = (_Float16)hnew;
      pvr[r] = hnew * wdj;
    }

    // -- decode partials: reduce over the 16 units of this (wave, b-group)
#pragma unroll
    for (int off = 1; off < 16; off <<= 1) {
      pvr[0] += __shfl_xor(pvr[0], off);
      pvr[1] += __shfl_xor(pvr[1], off);
      pvr[2] += __shfl_xor(pvr[2], off);
      pvr[3] += __shfl_xor(pvr[3], off);
    }
    if (l15 == 0)
      *(f32x4*)&pd[lt & 1][w][l4 * 4] =
          (f32x4){pvr[0], pvr[1], pvr[2], pvr[3]};

    // -- rotate prefetches; ONE barrier (lgkm only; vmcnt stays in flight)
#pragma unroll
    for (int r = 0; r < 4; ++r)
#pragma unroll
      for (int g3 = 0; g3 < 3; ++g3) xc[r][g3] = xn_[r][g3];
    g_hold = g_fut;
    BAR_LDS();
  }

  // ---- epilogue: NLL for step t1-1 (g_hold = gt[t1]); persist state ----
  if (tid < 16) {
    const int lt = t1 - 1 - t0;
    float p = bd0;
#pragma unroll
    for (int ww = 0; ww < 8; ++ww) p += pd[lt & 1][ww][tid];
    const float C = 1.f / (1.f + __expf(-p));
    nll0 -= g_hold * __logf(C + 1e-4f) +
            (1.f - g_hold) * __logf(1.f - C + 1e-4f);
    const int rr = row0 + tid;
    nll_part[rr] = first ? nll0 : (nll_part[rr] + nll0);
  }
#pragma unroll
  for (int r = 0; r < 4; ++r)
    ws_h[(size_t)(row0 + l4 * 4 + r) * H_DIM + u] = h_old[r];
}

// ---------------------------------------------------------------------------
__global__ __launch_bounds__(512) void k_fin(const float* __restrict__ nll_part,
                                             float* __restrict__ out) {
  __shared__ float red[8];
  const int tid = threadIdx.x;
  float v = nll_part[tid];
#pragma unroll
  for (int off = 32; off; off >>= 1) v += __shfl_down(v, off);
  if ((tid & 63) == 0) red[tid >> 6] = v;
  __syncthreads();
  if (tid == 0) {
    float s = 0.f;
#pragma unroll
    for (int i = 0; i < 8; ++i) s += red[i];
    out[0] = s * (1.f / (512.f * 512.f));
  }
}

// ---------------------------------------------------------------------------
extern "C" void kernel_launch(void* const* d_in, const int* in_sizes, int n_in,
                              void* d_out, int out_size, void* d_ws,
                              size_t ws_size, hipStream_t stream) {
  const float* x    = (const float*)d_in[0];
  const float* gt   = (const float*)d_in[1];
  const float* Wih  = (const float*)d_in[2];
  const float* Whh  = (const float*)d_in[3];
  const float* bih  = (const float*)d_in[4];
  const float* bhh  = (const float*)d_in[5];
  const float* Wdec = (const float*)d_in[6];
  const float* bdec = (const float*)d_in[7];

  // ws layout: [0,2KB) nll_part[512]; [4KB,260KB) h state; then xp chunk
  float* nll_part = (float*)d_ws;
  float* ws_h = (float*)((char*)d_ws + 4096);
  const size_t xp_off = 4096 + (size_t)B_DIM * H_DIM * 4;  // 266240
  _Float16* xp = (_Float16*)((char*)d_ws + xp_off);

  const size_t chunk_bytes = (size_t)B_DIM * G_DIM * 2;  // fp16 per timestep
  size_t avail = ws_size > xp_off ? ws_size - xp_off : 0;
  int Tc = (int)(avail / chunk_bytes);
  if (Tc > 128) Tc = 128;      // xp chunk <=50 MB, L3-resident
  if (Tc < 1) Tc = 1;

  for (int t0 = 0; t0 < STEPS; t0 += Tc) {
    int t1 = t0 + Tc;
    if (t1 > STEPS) t1 = STEPS;
    const int nt = t1 - t0;
    k_xproj<<<dim3(nt * 4), dim3(512), 0, stream>>>(
        x + (size_t)t0 * B_DIM * I_DIM, Wih, bih, bhh, xp);
    k_rec<<<dim3(32), dim3(512), 0, stream>>>(
        xp, gt, Whh, bhh, Wdec, bdec, ws_h, nll_part, t0, t1, t0 == 0 ? 1 : 0);
  }
  k_fin<<<dim3(1), dim3(512), 0, stream>>>(nll_part, (float*)d_out);
}